// Round 3
// baseline (150.440 us; speedup 1.0000x reference)
//
#include <hip/hip_runtime.h>

#define B_ 16
#define N_ 1024
#define F_ 16
#define E_ 12
#define H_ 4

// workspace layout (float offsets) — partials only; Q planes live in registers
#define OFF_PS 0        // 45056: self raw moments + x-sums per chunk [side*16+b][chunk8][176]
#define OFF_PC 45056    // 20480: cross moments per chunk [b][chunk8][160]
#define OFF_PK 65536    //  2048: Kabsch partial stats [b][chunk8][16] (15 used)
#define OFF_BAR 67584   //  4096: barrier slots [256 gm][16 ints]

// barrier epochs: slot value = MAGICB + phase (1..3). Spin accepts >= phase (monotone)
#define MAGICB 0x5AD7C100u

// moment layout per unit (39 used):
// [0:3]=Sum k | [3:9]=Sum kk (00,11,22,01,02,12) | [9:12]=Sum v
// [12:21]=Sum k_i v_c | [21:39]=Sum kk_pair v_c
// partS cols: [h*40 + j] for j<39, plus [160:176] = Sum x (16 features)

// shared-weight offsets
#define SW_WIN   0      // 192
#define SW_BIN   192    // 12
#define SW_WQKVS 204    // 432
#define SW_BQKVS 636    // 36
#define SW_WOS   672    // 144
#define SW_BOS   816    // 12
#define SW_WQKVC 828    // 432
#define SW_BQKVC 1260   // 36
#define SW_WOC   1296   // 144
#define SW_BOC   1440   // 12
#define SW_WOUT  1452   // 36
#define SW_BOUT  1488   // 3
#define SW_TOT   1491

__device__ __forceinline__ void mom_compute(float k0, float k1, float k2,
                                            float v0, float v1, float v2, float* m) {
  m[0]=k0; m[1]=k1; m[2]=k2;
  float s00=k0*k0, s11=k1*k1, s22=k2*k2, s01=k0*k1, s02=k0*k2, s12=k1*k2;
  m[3]=s00; m[4]=s11; m[5]=s22; m[6]=s01; m[7]=s02; m[8]=s12;
  m[9]=v0; m[10]=v1; m[11]=v2;
  m[12]=k0*v0; m[13]=k0*v1; m[14]=k0*v2;
  m[15]=k1*v0; m[16]=k1*v1; m[17]=k1*v2;
  m[18]=k2*v0; m[19]=k2*v1; m[20]=k2*v2;
  m[21]=s00*v0; m[22]=s00*v1; m[23]=s00*v2;
  m[24]=s11*v0; m[25]=s11*v1; m[26]=s11*v2;
  m[27]=s22*v0; m[28]=s22*v1; m[29]=s22*v2;
  m[30]=s01*v0; m[31]=s01*v1; m[32]=s01*v2;
  m[33]=s02*v0; m[34]=s02*v1; m[35]=s02*v2;
  m[36]=s12*v0; m[37]=s12*v1; m[38]=s12*v2;
}

// eval with pre-scaled moments (diag 2nd-order entries x0.5 applied at smu stage)
__device__ __forceinline__ void attn_eval(const float* __restrict__ mu,
                                          float p0, float p1, float p2, float* out) {
  float pp0=p0*p0, pp1=p1*p1, pp2=p2*p2;
  float q01=p0*p1, q02=p0*p2, q12=p1*p2;
  float den = (float)N_;
  den = fmaf(p0, mu[0], den); den = fmaf(p1, mu[1], den); den = fmaf(p2, mu[2], den);
  den = fmaf(pp0, mu[3], den); den = fmaf(pp1, mu[4], den); den = fmaf(pp2, mu[5], den);
  den = fmaf(q01, mu[6], den); den = fmaf(q02, mu[7], den); den = fmaf(q12, mu[8], den);
  float inv = 1.0f / den;
#pragma unroll
  for (int c = 0; c < 3; c++) {
    float num = mu[9+c];
    num = fmaf(p0, mu[12+c], num); num = fmaf(p1, mu[15+c], num); num = fmaf(p2, mu[18+c], num);
    num = fmaf(pp0, mu[21+c], num); num = fmaf(pp1, mu[24+c], num); num = fmaf(pp2, mu[27+c], num);
    num = fmaf(q01, mu[30+c], num); num = fmaf(q02, mu[33+c], num); num = fmaf(q12, mu[36+c], num);
    out[c] = num * inv;
  }
}

__device__ __forceinline__ float mom_scale(int j) {
  return ((j >= 3 && j < 6) || (j >= 21 && j < 30)) ? 0.5f : 1.0f;
}

// group software barrier over nmem blocks; slot value = MAGICB + phase, spin accepts >= phase.
// Relies on: (a) per-iteration ws re-poison (slots != magic range at start),
// (b) agent-scope fences for cross-XCD visibility, (c) capacity co-residency.
__device__ __forceinline__ void group_barrier(int* slots, int base, int my, int nmem,
                                              unsigned phase) {
  int tid = threadIdx.x;
  __threadfence();            // release: publish this thread's global stores
  __syncthreads();            // all block threads' stores published
  if (tid == 0)
    __hip_atomic_store(&slots[(base + my) * 16], (int)(MAGICB + phase),
                       __ATOMIC_RELEASE, __HIP_MEMORY_SCOPE_AGENT);
  if (tid < nmem) {
    for (;;) {
      unsigned v = (unsigned)__hip_atomic_load(&slots[(base + tid) * 16],
                       __ATOMIC_RELAXED, __HIP_MEMORY_SCOPE_AGENT);
      unsigned d = v - MAGICB;
      if (d >= phase && d <= 3u) break;
      __builtin_amdgcn_s_sleep(2);
    }
  }
  __syncthreads();
  __threadfence();            // acquire: invalidate stale cached lines
}

// ---- single kernel: A(proj) / B(self-attn+cross-proj) / C(cross-attn+stats) / D(polar+transform)
__global__ __launch_bounds__(128, 1)
void k_all(const float* __restrict__ xo, const float* __restrict__ yo,
           const float* __restrict__ W_in, const float* __restrict__ b_in,
           const float* __restrict__ Wqkv_s, const float* __restrict__ bqkv_s,
           const float* __restrict__ Wo_s, const float* __restrict__ bo_s,
           const float* __restrict__ Wqkv_c, const float* __restrict__ bqkv_c,
           const float* __restrict__ Wo_c, const float* __restrict__ bo_c,
           const float* __restrict__ W_out, const float* __restrict__ b_out,
           float* __restrict__ ws, float* __restrict__ out) {
  __shared__ float sw[SW_TOT];
  __shared__ float red[32 * 180];   // [quad32][176 used, stride 180]
  __shared__ float rawR[176];       // raw sums for this (side,b) — persists B..D
  __shared__ float smu[160];        // self moments (B), reused for cross moments (C)
  __shared__ float dq[12];
  __shared__ float sredK[2][15];
  __shared__ float sstats[15];
  __shared__ float myY[3];          // y mean (first 3 comps) — persists C..D

  float* partS = ws + OFF_PS;
  float* partC = ws + OFF_PC;
  float* partK = ws + OFF_PK;
  int*   slots = (int*)(ws + OFF_BAR);

  int tid = threadIdx.x;
  int blk = blockIdx.x;
  int side = blk >> 7;
  int rem  = blk & 127;
  int b = rem >> 3, c = rem & 7;
  int n = c * 128 + tid;
  int t = b * N_ + n;
  int qd = tid >> 2;
  bool rep = (tid & 3) == 0;
  const float SC = 0.57735026918962584f;   // 1/sqrt(3)
  const float invN = 1.0f / N_;

  // registers carried across barriers
  float qreg[12];                   // raw self-q per head (A -> B)
  float qc[12];                     // cross-q per head (B -> C, x side)
  float x30 = 0.f, x31 = 0.f, x32 = 0.f;  // centered x3 (C -> D, x side)

  // ---- load all weights once ----
  for (int i = tid; i < SW_TOT; i += 128) {
    float v;
    if (i < 192)       v = W_in[i];
    else if (i < 204)  v = b_in[i - 192];
    else if (i < 636)  v = Wqkv_s[i - 204];
    else if (i < 672)  v = bqkv_s[i - 636];
    else if (i < 816)  v = Wo_s[i - 672];
    else if (i < 828)  v = bo_s[i - 816];
    else if (i < 1260) v = Wqkv_c[i - 828];
    else if (i < 1296) v = bqkv_c[i - 1260];
    else if (i < 1440) v = Wo_c[i - 1296];
    else if (i < 1452) v = bo_c[i - 1440];
    else if (i < 1488) v = W_out[i - 1452];
    else               v = b_out[i - 1488];
    sw[i] = v;
  }

  // ================= Phase A: raw proj + self QKV + raw moments =================
  const float* in = (side ? yo : xo) + (size_t)t * F_;
  float xv[F_];
  {
    const float4* p = (const float4*)in;
#pragma unroll
    for (int q = 0; q < 4; q++) {
      float4 v = p[q];
      xv[4*q+0]=v.x; xv[4*q+1]=v.y; xv[4*q+2]=v.z; xv[4*q+3]=v.w;
    }
  }
  __syncthreads();          // sw ready
  float xi[E_];             // raw (uncentered) xi' = x@W_in^T + b_in
#pragma unroll
  for (int e = 0; e < E_; e++) {
    float s = sw[SW_BIN + e];
#pragma unroll
    for (int f = 0; f < F_; f++) s = fmaf(xv[f], sw[SW_WIN + e*F_ + f], s);
    xi[e] = s;
  }
#pragma unroll
  for (int h = 0; h < H_; h++) {
    float qkv[9];
#pragma unroll
    for (int d = 0; d < 9; d++) {
      int o = (d/3)*12 + h*3 + (d%3);   // q=h*3+c, k=12+h*3+c, v=24+h*3+c
      float s = sw[SW_BQKVS + o];
#pragma unroll
      for (int e = 0; e < E_; e++) s = fmaf(xi[e], sw[SW_WQKVS + o*E_ + e], s);
      qkv[d] = s;
    }
#pragma unroll
    for (int d = 0; d < 3; d++) qreg[h*3+d] = qkv[d];
    float m[40];
    mom_compute(qkv[3], qkv[4], qkv[5], qkv[6], qkv[7], qkv[8], m);
    m[39] = 0.f;
#pragma unroll
    for (int j = 0; j < 39; j++) {
      m[j] += __shfl_xor(m[j], 1);
      m[j] += __shfl_xor(m[j], 2);
    }
    if (rep) {
#pragma unroll
      for (int j4 = 0; j4 < 10; j4++)
        *(float4*)&red[qd*180 + h*40 + j4*4] =
          make_float4(m[j4*4], m[j4*4+1], m[j4*4+2], m[j4*4+3]);
    }
  }
  {
    float s[F_];
#pragma unroll
    for (int f = 0; f < F_; f++) {
      float v = xv[f];
      v += __shfl_xor(v, 1);
      v += __shfl_xor(v, 2);
      s[f] = v;
    }
    if (rep) {
#pragma unroll
      for (int j4 = 0; j4 < 4; j4++)
        *(float4*)&red[qd*180 + 160 + j4*4] =
          make_float4(s[j4*4], s[j4*4+1], s[j4*4+2], s[j4*4+3]);
    }
  }
  __syncthreads();
  for (int col = tid; col < 176; col += 128) {
    float a = 0.f;
#pragma unroll
    for (int qq = 0; qq < 32; qq++) a += red[qq*180 + col];
    partS[((size_t)(side*16 + b)*8 + c)*176 + col] = a;
  }

  // barrier 1: the 8 blocks of this (side,b)
  group_barrier(slots, b*16 + side*8, c, 8, 1u);

  // ================= Phase B: moment correction + self-attn + cross QKV =================
  for (int col = tid; col < 176; col += 128) {
    float a = 0.f;
#pragma unroll
    for (int cc = 0; cc < 8; cc++)
      a += partS[((size_t)(side*16 + b)*8 + cc)*176 + col];
    rawR[col] = a;
  }
  __syncthreads();
  if (tid < H_) {
    int h = tid;
    const float Nf = (float)N_;
    float del[E_];               // delta = mu @ W_in^T   (no bias)
#pragma unroll
    for (int e = 0; e < E_; e++) {
      float s = 0.f;
#pragma unroll
      for (int f = 0; f < F_; f++) s = fmaf(rawR[160+f], sw[SW_WIN + e*F_ + f], s);
      del[e] = s * invN;
    }
    float A[3], G[3];            // k-shift, v-shift for this head
#pragma unroll
    for (int d = 0; d < 3; d++) {
      float sq=0.f, sk=0.f, sv=0.f;
#pragma unroll
      for (int e = 0; e < E_; e++) {
        sq = fmaf(del[e], sw[SW_WQKVS + (h*3+d)*E_ + e], sq);
        sk = fmaf(del[e], sw[SW_WQKVS + (12 + h*3+d)*E_ + e], sk);
        sv = fmaf(del[e], sw[SW_WQKVS + (24 + h*3+d)*E_ + e], sv);
      }
      dq[h*3+d] = sq; A[d] = sk; G[d] = sv;
    }
    const float* R = &rawR[h*40];
    float S[39];
#pragma unroll
    for (int i = 0; i < 3; i++) S[i] = R[i] - Nf*A[i];
    const int PI[6] = {0,1,2,0,0,1}, PJ[6] = {0,1,2,1,2,2};
#pragma unroll
    for (int p = 0; p < 6; p++) {
      int i = PI[p], j = PJ[p];
      S[3+p] = R[3+p] - A[i]*R[j] - A[j]*R[i] + Nf*A[i]*A[j];
    }
#pragma unroll
    for (int cc = 0; cc < 3; cc++) S[9+cc] = R[9+cc] - Nf*G[cc];
#pragma unroll
    for (int i = 0; i < 3; i++)
#pragma unroll
      for (int cc = 0; cc < 3; cc++)
        S[12+i*3+cc] = R[12+i*3+cc] - A[i]*R[9+cc] - G[cc]*R[i] + Nf*A[i]*G[cc];
#pragma unroll
    for (int p = 0; p < 6; p++) {
      int i = PI[p], j = PJ[p];
#pragma unroll
      for (int cc = 0; cc < 3; cc++) {
        S[21+p*3+cc] = R[21+p*3+cc]
                     - A[i]*R[12+j*3+cc] - A[j]*R[12+i*3+cc]
                     - G[cc]*R[3+p]
                     + A[i]*A[j]*R[9+cc]
                     + A[i]*G[cc]*R[j] + A[j]*G[cc]*R[i]
                     - Nf*A[i]*A[j]*G[cc];
      }
    }
#pragma unroll
    for (int j = 0; j < 39; j++) smu[h*40+j] = S[j] * mom_scale(j);
    smu[h*40+39] = 0.f;
  }
  __syncthreads();
  {
    float attn[E_];
#pragma unroll
    for (int h = 0; h < H_; h++) {
      float p0 = (qreg[h*3+0] - dq[h*3+0]) * SC;
      float p1 = (qreg[h*3+1] - dq[h*3+1]) * SC;
      float p2 = (qreg[h*3+2] - dq[h*3+2]) * SC;
      attn_eval(&smu[h*40], p0, p1, p2, &attn[h*3]);
    }
    float i2[E_];
#pragma unroll
    for (int e = 0; e < E_; e++) {
      float s = sw[SW_BOS + e];
#pragma unroll
      for (int j = 0; j < E_; j++) s = fmaf(attn[j], sw[SW_WOS + e*E_ + j], s);
      i2[e] = s;
    }
    if (!side) {                      // x side -> cross-q stays in registers
#pragma unroll
      for (int o = 0; o < 12; o++) {
        float s = sw[SW_BQKVC + o];
#pragma unroll
        for (int e = 0; e < E_; e++) s = fmaf(i2[e], sw[SW_WQKVC + o*E_ + e], s);
        qc[o] = s;
      }
    } else {                          // y side -> cross moments (centered, no fixup)
#pragma unroll
      for (int h = 0; h < H_; h++) {
        float kv[6];
#pragma unroll
        for (int d = 0; d < 6; d++) {
          int o = 12 + (d/3)*12 + h*3 + (d%3);
          float s = sw[SW_BQKVC + o];
#pragma unroll
          for (int e = 0; e < E_; e++) s = fmaf(i2[e], sw[SW_WQKVC + o*E_ + e], s);
          kv[d] = s;
        }
        float m[40];
        mom_compute(kv[0], kv[1], kv[2], kv[3], kv[4], kv[5], m);
        m[39] = 0.f;
#pragma unroll
        for (int j = 0; j < 39; j++) {
          m[j] += __shfl_xor(m[j], 1);
          m[j] += __shfl_xor(m[j], 2);
        }
        if (rep) {
#pragma unroll
          for (int j4 = 0; j4 < 10; j4++)
            *(float4*)&red[qd*180 + h*40 + j4*4] =
              make_float4(m[j4*4], m[j4*4+1], m[j4*4+2], m[j4*4+3]);
        }
      }
      __syncthreads();                // block-uniform branch (side per block)
      for (int col = tid; col < 160; col += 128) {
        float a = 0.f;
#pragma unroll
        for (int qq = 0; qq < 32; qq++) a += red[qq*180 + col];
        partC[((size_t)b*8 + c)*160 + col] = a;
      }
    }
  }

  // barrier 2: the 16 blocks (both sides) of batch b
  group_barrier(slots, b*16, side*8 + c, 16, 2u);
  if (side) return;                   // y blocks done

  // ================= Phase C: cross-attn + Kabsch partial stats (x blocks) =================
  {
    for (int col = tid; col < 160; col += 128) {
      float a = 0.f;
#pragma unroll
      for (int cc = 0; cc < 8; cc++) a += partC[((size_t)b*8 + cc)*160 + col];
      int j = col - (col/40)*40;
      smu[col] = a * mom_scale(j);
    }
    if (tid < 3) {
      float a = 0.f;
#pragma unroll
      for (int cc = 0; cc < 8; cc++)
        a += partS[((size_t)(16 + b)*8 + cc)*176 + 160 + tid];
      myY[tid] = a * invN;
    }
    __syncthreads();
    float attn[E_];
#pragma unroll
    for (int h = 0; h < H_; h++) {
      float p0 = qc[h*3+0] * SC;
      float p1 = qc[h*3+1] * SC;
      float p2 = qc[h*3+2] * SC;
      attn_eval(&smu[h*40], p0, p1, p2, &attn[h*3]);
    }
    float c12[E_];
#pragma unroll
    for (int e = 0; e < E_; e++) {
      float s = sw[SW_BOC + e];
#pragma unroll
      for (int j = 0; j < E_; j++) s = fmaf(attn[j], sw[SW_WOC + e*E_ + j], s);
      c12[e] = s;
    }
    float co[3];
#pragma unroll
    for (int k = 0; k < 3; k++) {
      float s = sw[SW_BOUT + k];
#pragma unroll
      for (int e = 0; e < E_; e++) s = fmaf(c12[e], sw[SW_WOUT + k*E_ + e], s);
      co[k] = s;
    }
    x30 = xv[0] - rawR[160] * invN;   // rawR persists from phase B (this block: x sums)
    x31 = xv[1] - rawR[161] * invN;
    x32 = xv[2] - rawR[162] * invN;
    float A0 = co[0]+x30, A1 = co[1]+x31, A2 = co[2]+x32;
    float st[15];
    st[0]=co[0]; st[1]=co[1]; st[2]=co[2];
    st[3]=x30; st[4]=x31; st[5]=x32;
    st[6]=x30*A0;  st[7]=x30*A1;  st[8]=x30*A2;
    st[9]=x31*A0;  st[10]=x31*A1; st[11]=x31*A2;
    st[12]=x32*A0; st[13]=x32*A1; st[14]=x32*A2;
#pragma unroll
    for (int i = 0; i < 15; i++) {
      st[i] += __shfl_down(st[i], 32); st[i] += __shfl_down(st[i], 16);
      st[i] += __shfl_down(st[i], 8);  st[i] += __shfl_down(st[i], 4);
      st[i] += __shfl_down(st[i], 2);  st[i] += __shfl_down(st[i], 1);
    }
    int wv = tid >> 6;
    if ((tid & 63) == 0) {
#pragma unroll
      for (int i = 0; i < 15; i++) sredK[wv][i] = st[i];
    }
    __syncthreads();
    if (tid < 15) partK[((size_t)b*8 + c)*16 + tid] = sredK[0][tid] + sredK[1][tid];
  }

  // barrier 3: the 8 x-blocks of batch b (reuse x-side slots with epoch 3)
  group_barrier(slots, b*16, c, 8, 3u);

  // ================= Phase D: polar + rigid transform (x blocks) =================
  {
    if (tid < 15) {
      float a = 0.f;
#pragma unroll
      for (int cc = 0; cc < 8; cc++) a += partK[((size_t)b*8 + cc)*16 + tid];
      sstats[tid] = a;
    }
    __syncthreads();
    const float* s = sstats;
    float cB[3] = { s[3]*invN, s[4]*invN, s[5]*invN };
    float cA[3] = { (s[0]+s[3])*invN, (s[1]+s[4])*invN, (s[2]+s[5])*invN };
    float X[9];
#pragma unroll
    for (int i = 0; i < 3; i++)
#pragma unroll
      for (int j = 0; j < 3; j++)
        X[i*3+j] = s[6 + i*3 + j] - (float)N_ * cB[i] * cA[j];
    float fn = 0.f;
#pragma unroll
    for (int i = 0; i < 9; i++) fn += X[i]*X[i];
    float scl = rsqrtf(fn);
#pragma unroll
    for (int i = 0; i < 9; i++) X[i] *= scl;
    for (int it = 0; it < 24; it++) {
      float c00 =  X[4]*X[8]-X[5]*X[7];
      float c01 = -(X[3]*X[8]-X[5]*X[6]);
      float c02 =  X[3]*X[7]-X[4]*X[6];
      float c10 = -(X[1]*X[8]-X[2]*X[7]);
      float c11 =  X[0]*X[8]-X[2]*X[6];
      float c12_= -(X[0]*X[7]-X[1]*X[6]);
      float c20 =  X[1]*X[5]-X[2]*X[4];
      float c21 = -(X[0]*X[5]-X[2]*X[3]);
      float c22 =  X[0]*X[4]-X[1]*X[3];
      float det = X[0]*c00 + X[1]*c01 + X[2]*c02;
      float id = 0.5f / det;
      X[0]=0.5f*X[0]+c00*id; X[1]=0.5f*X[1]+c01*id; X[2]=0.5f*X[2]+c02*id;
      X[3]=0.5f*X[3]+c10*id; X[4]=0.5f*X[4]+c11*id; X[5]=0.5f*X[5]+c12_*id;
      X[6]=0.5f*X[6]+c20*id; X[7]=0.5f*X[7]+c21*id; X[8]=0.5f*X[8]+c22*id;
    }
    float tt[3];
#pragma unroll
    for (int k = 0; k < 3; k++)
      tt[k] = cA[k] - (cB[0]*X[k] + cB[1]*X[3+k] + cB[2]*X[6+k]) + myY[k];
#pragma unroll
    for (int k = 0; k < 3; k++) {
      float v = fmaf(x30, X[k], fmaf(x31, X[3+k], fmaf(x32, X[6+k], tt[k])));
      out[(size_t)t*3 + k] = v;
    }
  }
}

extern "C" void kernel_launch(void* const* d_in, const int* in_sizes, int n_in,
                              void* d_out, int out_size, void* d_ws, size_t ws_size,
                              hipStream_t stream) {
  const float* x_orig = (const float*)d_in[0];
  const float* y_orig = (const float*)d_in[1];
  const float* W_in   = (const float*)d_in[2];
  const float* b_in   = (const float*)d_in[3];
  const float* Wqkv_s = (const float*)d_in[4];
  const float* bqkv_s = (const float*)d_in[5];
  const float* Wo_s   = (const float*)d_in[6];
  const float* bo_s   = (const float*)d_in[7];
  const float* Wqkv_c = (const float*)d_in[8];
  const float* bqkv_c = (const float*)d_in[9];
  const float* Wo_c   = (const float*)d_in[10];
  const float* bo_c   = (const float*)d_in[11];
  const float* W_out  = (const float*)d_in[12];
  const float* b_out  = (const float*)d_in[13];
  float* ws  = (float*)d_ws;

  k_all<<<256, 128, 0, stream>>>(x_orig, y_orig, W_in, b_in, Wqkv_s, bqkv_s,
                                 Wo_s, bo_s, Wqkv_c, bqkv_c, Wo_c, bo_c,
                                 W_out, b_out, ws, (float*)d_out);
}

// Round 4
// 119.422 us; speedup vs baseline: 1.2597x; 1.2597x over previous
//
#include <hip/hip_runtime.h>

#define B_ 16
#define N_ 1024
#define F_ 16
#define E_ 12
#define H_ 4

// workspace layout in u64 slots — each slot = {tag:32, float_bits:32}, relaxed agent atomics
#define SLOT_PS 0       // 45056: self raw moments + x-sums per chunk [side*16+b][chunk8][176]
#define SLOT_PC 45056   // 20480: cross moments per chunk [b][chunk8][160]
#define SLOT_PK 65536   //  2048: Kabsch partial stats [b][chunk8][16] (15 used)

#define TAG_S 0x51A7E00Du
#define TAG_C 0x51A7E0C5u
#define TAG_K 0x51A7E0B3u

// moment layout per unit (39 used):
// [0:3]=Sum k | [3:9]=Sum kk (00,11,22,01,02,12) | [9:12]=Sum v
// [12:21]=Sum k_i v_c | [21:39]=Sum kk_pair v_c
// partS cols: [h*40 + j] for j<39, plus [160:176] = Sum x (16 features)

// shared-weight offsets
#define SW_WIN   0      // 192
#define SW_BIN   192    // 12
#define SW_WQKVS 204    // 432
#define SW_BQKVS 636    // 36
#define SW_WOS   672    // 144
#define SW_BOS   816    // 12
#define SW_WQKVC 828    // 432
#define SW_BQKVC 1260   // 36
#define SW_WOC   1296   // 144
#define SW_BOC   1440   // 12
#define SW_WOUT  1452   // 36
#define SW_BOUT  1488   // 3
#define SW_TOT   1491

__device__ __forceinline__ void slot_store(unsigned long long* p, float f, unsigned tag) {
  unsigned long long v = ((unsigned long long)tag << 32) | (unsigned long long)__float_as_uint(f);
  __hip_atomic_store(p, v, __ATOMIC_RELAXED, __HIP_MEMORY_SCOPE_AGENT);
}

// wait for 8 tagged slots (stride STRIDE u64s apart), then sum in fixed order (deterministic)
template<int STRIDE>
__device__ __forceinline__ float gather8(unsigned long long* base, unsigned tag) {
  float vals[8];
  unsigned pend = 0xffu;
  while (pend) {
    unsigned np = 0;
#pragma unroll
    for (int cc = 0; cc < 8; cc++) {
      if (pend & (1u << cc)) {
        unsigned long long v = __hip_atomic_load(base + (size_t)cc * STRIDE,
                                                 __ATOMIC_RELAXED, __HIP_MEMORY_SCOPE_AGENT);
        if ((unsigned)(v >> 32) == tag)
          vals[cc] = __uint_as_float((unsigned)(v & 0xffffffffu));
        else
          np |= 1u << cc;
      }
    }
    pend = np;
    if (pend) __builtin_amdgcn_s_sleep(1);
  }
  float a = 0.f;
#pragma unroll
  for (int cc = 0; cc < 8; cc++) a += vals[cc];
  return a;
}

__device__ __forceinline__ void mom_compute(float k0, float k1, float k2,
                                            float v0, float v1, float v2, float* m) {
  m[0]=k0; m[1]=k1; m[2]=k2;
  float s00=k0*k0, s11=k1*k1, s22=k2*k2, s01=k0*k1, s02=k0*k2, s12=k1*k2;
  m[3]=s00; m[4]=s11; m[5]=s22; m[6]=s01; m[7]=s02; m[8]=s12;
  m[9]=v0; m[10]=v1; m[11]=v2;
  m[12]=k0*v0; m[13]=k0*v1; m[14]=k0*v2;
  m[15]=k1*v0; m[16]=k1*v1; m[17]=k1*v2;
  m[18]=k2*v0; m[19]=k2*v1; m[20]=k2*v2;
  m[21]=s00*v0; m[22]=s00*v1; m[23]=s00*v2;
  m[24]=s11*v0; m[25]=s11*v1; m[26]=s11*v2;
  m[27]=s22*v0; m[28]=s22*v1; m[29]=s22*v2;
  m[30]=s01*v0; m[31]=s01*v1; m[32]=s01*v2;
  m[33]=s02*v0; m[34]=s02*v1; m[35]=s02*v2;
  m[36]=s12*v0; m[37]=s12*v1; m[38]=s12*v2;
}

// eval with pre-scaled moments (diag 2nd-order entries x0.5 applied at smu stage)
__device__ __forceinline__ void attn_eval(const float* __restrict__ mu,
                                          float p0, float p1, float p2, float* out) {
  float pp0=p0*p0, pp1=p1*p1, pp2=p2*p2;
  float q01=p0*p1, q02=p0*p2, q12=p1*p2;
  float den = (float)N_;
  den = fmaf(p0, mu[0], den); den = fmaf(p1, mu[1], den); den = fmaf(p2, mu[2], den);
  den = fmaf(pp0, mu[3], den); den = fmaf(pp1, mu[4], den); den = fmaf(pp2, mu[5], den);
  den = fmaf(q01, mu[6], den); den = fmaf(q02, mu[7], den); den = fmaf(q12, mu[8], den);
  float inv = 1.0f / den;
#pragma unroll
  for (int c = 0; c < 3; c++) {
    float num = mu[9+c];
    num = fmaf(p0, mu[12+c], num); num = fmaf(p1, mu[15+c], num); num = fmaf(p2, mu[18+c], num);
    num = fmaf(pp0, mu[21+c], num); num = fmaf(pp1, mu[24+c], num); num = fmaf(pp2, mu[27+c], num);
    num = fmaf(q01, mu[30+c], num); num = fmaf(q02, mu[33+c], num); num = fmaf(q12, mu[36+c], num);
    out[c] = num * inv;
  }
}

__device__ __forceinline__ float mom_scale(int j) {
  return ((j >= 3 && j < 6) || (j >= 21 && j < 30)) ? 0.5f : 1.0f;
}

// ---- single kernel: A(proj) / B(self-attn+cross-proj) / C(cross-attn+stats) / D(polar+transform)
// Cross-block dataflow via tagged u64 relaxed agent atomics — no fences, no barriers.
__global__ __launch_bounds__(128, 1)
void k_all(const float* __restrict__ xo, const float* __restrict__ yo,
           const float* __restrict__ W_in, const float* __restrict__ b_in,
           const float* __restrict__ Wqkv_s, const float* __restrict__ bqkv_s,
           const float* __restrict__ Wo_s, const float* __restrict__ bo_s,
           const float* __restrict__ Wqkv_c, const float* __restrict__ bqkv_c,
           const float* __restrict__ Wo_c, const float* __restrict__ bo_c,
           const float* __restrict__ W_out, const float* __restrict__ b_out,
           unsigned long long* __restrict__ ws, float* __restrict__ out) {
  __shared__ float sw[SW_TOT];
  __shared__ float red[32 * 180];   // [quad32][176 used, stride 180]
  __shared__ float rawR[176];       // raw sums for this (side,b) — persists B..D
  __shared__ float smu[160];        // self moments (B), reused for cross moments (C)
  __shared__ float dq[12];
  __shared__ float sredK[2][15];
  __shared__ float sstats[15];
  __shared__ float myY[3];          // y mean (first 3 comps) — persists C..D

  unsigned long long* psS = ws + SLOT_PS;
  unsigned long long* psC = ws + SLOT_PC;
  unsigned long long* psK = ws + SLOT_PK;

  int tid = threadIdx.x;
  int blk = blockIdx.x;
  int side = blk >> 7;
  int rem  = blk & 127;
  int b = rem >> 3, c = rem & 7;
  int n = c * 128 + tid;
  int t = b * N_ + n;
  int qd = tid >> 2;
  bool rep = (tid & 3) == 0;
  const float SC = 0.57735026918962584f;   // 1/sqrt(3)
  const float invN = 1.0f / N_;

  // registers carried across phases
  float qreg[12];                   // raw self-q per head (A -> B)
  float qc[12];                     // cross-q per head (B -> C, x side)
  float x30 = 0.f, x31 = 0.f, x32 = 0.f;  // centered x3 (C -> D, x side)

  // ---- load all weights once ----
  for (int i = tid; i < SW_TOT; i += 128) {
    float v;
    if (i < 192)       v = W_in[i];
    else if (i < 204)  v = b_in[i - 192];
    else if (i < 636)  v = Wqkv_s[i - 204];
    else if (i < 672)  v = bqkv_s[i - 636];
    else if (i < 816)  v = Wo_s[i - 672];
    else if (i < 828)  v = bo_s[i - 816];
    else if (i < 1260) v = Wqkv_c[i - 828];
    else if (i < 1296) v = bqkv_c[i - 1260];
    else if (i < 1440) v = Wo_c[i - 1296];
    else if (i < 1452) v = bo_c[i - 1440];
    else if (i < 1488) v = W_out[i - 1452];
    else               v = b_out[i - 1488];
    sw[i] = v;
  }

  // ================= Phase A: raw proj + self QKV + raw moments =================
  const float* in = (side ? yo : xo) + (size_t)t * F_;
  float xv[F_];
  {
    const float4* p = (const float4*)in;
#pragma unroll
    for (int q = 0; q < 4; q++) {
      float4 v = p[q];
      xv[4*q+0]=v.x; xv[4*q+1]=v.y; xv[4*q+2]=v.z; xv[4*q+3]=v.w;
    }
  }
  __syncthreads();          // sw ready
  float xi[E_];             // raw (uncentered) xi' = x@W_in^T + b_in
#pragma unroll
  for (int e = 0; e < E_; e++) {
    float s = sw[SW_BIN + e];
#pragma unroll
    for (int f = 0; f < F_; f++) s = fmaf(xv[f], sw[SW_WIN + e*F_ + f], s);
    xi[e] = s;
  }
#pragma unroll
  for (int h = 0; h < H_; h++) {
    float qkv[9];
#pragma unroll
    for (int d = 0; d < 9; d++) {
      int o = (d/3)*12 + h*3 + (d%3);   // q=h*3+c, k=12+h*3+c, v=24+h*3+c
      float s = sw[SW_BQKVS + o];
#pragma unroll
      for (int e = 0; e < E_; e++) s = fmaf(xi[e], sw[SW_WQKVS + o*E_ + e], s);
      qkv[d] = s;
    }
#pragma unroll
    for (int d = 0; d < 3; d++) qreg[h*3+d] = qkv[d];
    float m[40];
    mom_compute(qkv[3], qkv[4], qkv[5], qkv[6], qkv[7], qkv[8], m);
    m[39] = 0.f;
#pragma unroll
    for (int j = 0; j < 39; j++) {
      m[j] += __shfl_xor(m[j], 1);
      m[j] += __shfl_xor(m[j], 2);
    }
    if (rep) {
#pragma unroll
      for (int j4 = 0; j4 < 10; j4++)
        *(float4*)&red[qd*180 + h*40 + j4*4] =
          make_float4(m[j4*4], m[j4*4+1], m[j4*4+2], m[j4*4+3]);
    }
  }
  {
    float s[F_];
#pragma unroll
    for (int f = 0; f < F_; f++) {
      float v = xv[f];
      v += __shfl_xor(v, 1);
      v += __shfl_xor(v, 2);
      s[f] = v;
    }
    if (rep) {
#pragma unroll
      for (int j4 = 0; j4 < 4; j4++)
        *(float4*)&red[qd*180 + 160 + j4*4] =
          make_float4(s[j4*4], s[j4*4+1], s[j4*4+2], s[j4*4+3]);
    }
  }
  __syncthreads();
  for (int col = tid; col < 176; col += 128) {
    float a = 0.f;
#pragma unroll
    for (int qq = 0; qq < 32; qq++) a += red[qq*180 + col];
    slot_store(&psS[((size_t)(side*16 + b)*8 + c)*176 + col], a, TAG_S);
  }

  // ================= Phase B: moment correction + self-attn + cross QKV =================
  for (int col = tid; col < 176; col += 128) {
    rawR[col] = gather8<176>(&psS[(size_t)(side*16 + b)*8*176 + col], TAG_S);
  }
  __syncthreads();
  if (tid < H_) {
    int h = tid;
    const float Nf = (float)N_;
    float del[E_];               // delta = mu @ W_in^T   (no bias)
#pragma unroll
    for (int e = 0; e < E_; e++) {
      float s = 0.f;
#pragma unroll
      for (int f = 0; f < F_; f++) s = fmaf(rawR[160+f], sw[SW_WIN + e*F_ + f], s);
      del[e] = s * invN;
    }
    float A[3], G[3];            // k-shift, v-shift for this head
#pragma unroll
    for (int d = 0; d < 3; d++) {
      float sq=0.f, sk=0.f, sv=0.f;
#pragma unroll
      for (int e = 0; e < E_; e++) {
        sq = fmaf(del[e], sw[SW_WQKVS + (h*3+d)*E_ + e], sq);
        sk = fmaf(del[e], sw[SW_WQKVS + (12 + h*3+d)*E_ + e], sk);
        sv = fmaf(del[e], sw[SW_WQKVS + (24 + h*3+d)*E_ + e], sv);
      }
      dq[h*3+d] = sq; A[d] = sk; G[d] = sv;
    }
    const float* R = &rawR[h*40];
    float S[39];
#pragma unroll
    for (int i = 0; i < 3; i++) S[i] = R[i] - Nf*A[i];
    const int PI[6] = {0,1,2,0,0,1}, PJ[6] = {0,1,2,1,2,2};
#pragma unroll
    for (int p = 0; p < 6; p++) {
      int i = PI[p], j = PJ[p];
      S[3+p] = R[3+p] - A[i]*R[j] - A[j]*R[i] + Nf*A[i]*A[j];
    }
#pragma unroll
    for (int cc = 0; cc < 3; cc++) S[9+cc] = R[9+cc] - Nf*G[cc];
#pragma unroll
    for (int i = 0; i < 3; i++)
#pragma unroll
      for (int cc = 0; cc < 3; cc++)
        S[12+i*3+cc] = R[12+i*3+cc] - A[i]*R[9+cc] - G[cc]*R[i] + Nf*A[i]*G[cc];
#pragma unroll
    for (int p = 0; p < 6; p++) {
      int i = PI[p], j = PJ[p];
#pragma unroll
      for (int cc = 0; cc < 3; cc++) {
        S[21+p*3+cc] = R[21+p*3+cc]
                     - A[i]*R[12+j*3+cc] - A[j]*R[12+i*3+cc]
                     - G[cc]*R[3+p]
                     + A[i]*A[j]*R[9+cc]
                     + A[i]*G[cc]*R[j] + A[j]*G[cc]*R[i]
                     - Nf*A[i]*A[j]*G[cc];
      }
    }
#pragma unroll
    for (int j = 0; j < 39; j++) smu[h*40+j] = S[j] * mom_scale(j);
    smu[h*40+39] = 0.f;
  }
  __syncthreads();
  {
    float attn[E_];
#pragma unroll
    for (int h = 0; h < H_; h++) {
      float p0 = (qreg[h*3+0] - dq[h*3+0]) * SC;
      float p1 = (qreg[h*3+1] - dq[h*3+1]) * SC;
      float p2 = (qreg[h*3+2] - dq[h*3+2]) * SC;
      attn_eval(&smu[h*40], p0, p1, p2, &attn[h*3]);
    }
    float i2[E_];
#pragma unroll
    for (int e = 0; e < E_; e++) {
      float s = sw[SW_BOS + e];
#pragma unroll
      for (int j = 0; j < E_; j++) s = fmaf(attn[j], sw[SW_WOS + e*E_ + j], s);
      i2[e] = s;
    }
    if (!side) {                      // x side -> cross-q stays in registers
#pragma unroll
      for (int o = 0; o < 12; o++) {
        float s = sw[SW_BQKVC + o];
#pragma unroll
        for (int e = 0; e < E_; e++) s = fmaf(i2[e], sw[SW_WQKVC + o*E_ + e], s);
        qc[o] = s;
      }
    } else {                          // y side -> cross moments (centered, no fixup)
#pragma unroll
      for (int h = 0; h < H_; h++) {
        float kv[6];
#pragma unroll
        for (int d = 0; d < 6; d++) {
          int o = 12 + (d/3)*12 + h*3 + (d%3);
          float s = sw[SW_BQKVC + o];
#pragma unroll
          for (int e = 0; e < E_; e++) s = fmaf(i2[e], sw[SW_WQKVC + o*E_ + e], s);
          kv[d] = s;
        }
        float m[40];
        mom_compute(kv[0], kv[1], kv[2], kv[3], kv[4], kv[5], m);
        m[39] = 0.f;
#pragma unroll
        for (int j = 0; j < 39; j++) {
          m[j] += __shfl_xor(m[j], 1);
          m[j] += __shfl_xor(m[j], 2);
        }
        if (rep) {
#pragma unroll
          for (int j4 = 0; j4 < 10; j4++)
            *(float4*)&red[qd*180 + h*40 + j4*4] =
              make_float4(m[j4*4], m[j4*4+1], m[j4*4+2], m[j4*4+3]);
        }
      }
      __syncthreads();                // block-uniform branch (side per block)
      for (int col = tid; col < 160; col += 128) {
        float a = 0.f;
#pragma unroll
        for (int qq = 0; qq < 32; qq++) a += red[qq*180 + col];
        slot_store(&psC[((size_t)b*8 + c)*160 + col], a, TAG_C);
      }
      return;                         // y blocks done
    }
  }

  // ================= Phase C: cross-attn + Kabsch partial stats (x blocks) =================
  {
    for (int col = tid; col < 160; col += 128) {
      float a = gather8<160>(&psC[(size_t)b*8*160 + col], TAG_C);
      int j = col - (col/40)*40;
      smu[col] = a * mom_scale(j);
    }
    if (tid < 3) {
      float a = gather8<176>(&psS[(size_t)(16 + b)*8*176 + 160 + tid], TAG_S);
      myY[tid] = a * invN;
    }
    __syncthreads();
    float attn[E_];
#pragma unroll
    for (int h = 0; h < H_; h++) {
      float p0 = qc[h*3+0] * SC;
      float p1 = qc[h*3+1] * SC;
      float p2 = qc[h*3+2] * SC;
      attn_eval(&smu[h*40], p0, p1, p2, &attn[h*3]);
    }
    float c12[E_];
#pragma unroll
    for (int e = 0; e < E_; e++) {
      float s = sw[SW_BOC + e];
#pragma unroll
      for (int j = 0; j < E_; j++) s = fmaf(attn[j], sw[SW_WOC + e*E_ + j], s);
      c12[e] = s;
    }
    float co[3];
#pragma unroll
    for (int k = 0; k < 3; k++) {
      float s = sw[SW_BOUT + k];
#pragma unroll
      for (int e = 0; e < E_; e++) s = fmaf(c12[e], sw[SW_WOUT + k*E_ + e], s);
      co[k] = s;
    }
    x30 = xv[0] - rawR[160] * invN;   // rawR persists from phase B (this block: x sums)
    x31 = xv[1] - rawR[161] * invN;
    x32 = xv[2] - rawR[162] * invN;
    float A0 = co[0]+x30, A1 = co[1]+x31, A2 = co[2]+x32;
    float st[15];
    st[0]=co[0]; st[1]=co[1]; st[2]=co[2];
    st[3]=x30; st[4]=x31; st[5]=x32;
    st[6]=x30*A0;  st[7]=x30*A1;  st[8]=x30*A2;
    st[9]=x31*A0;  st[10]=x31*A1; st[11]=x31*A2;
    st[12]=x32*A0; st[13]=x32*A1; st[14]=x32*A2;
#pragma unroll
    for (int i = 0; i < 15; i++) {
      st[i] += __shfl_down(st[i], 32); st[i] += __shfl_down(st[i], 16);
      st[i] += __shfl_down(st[i], 8);  st[i] += __shfl_down(st[i], 4);
      st[i] += __shfl_down(st[i], 2);  st[i] += __shfl_down(st[i], 1);
    }
    int wv = tid >> 6;
    if ((tid & 63) == 0) {
#pragma unroll
      for (int i = 0; i < 15; i++) sredK[wv][i] = st[i];
    }
    __syncthreads();
    if (tid < 15)
      slot_store(&psK[((size_t)b*8 + c)*16 + tid], sredK[0][tid] + sredK[1][tid], TAG_K);
  }

  // ================= Phase D: polar + rigid transform (x blocks) =================
  {
    if (tid < 15) {
      sstats[tid] = gather8<16>(&psK[(size_t)b*8*16 + tid], TAG_K);
    }
    __syncthreads();
    const float* s = sstats;
    float cB[3] = { s[3]*invN, s[4]*invN, s[5]*invN };
    float cA[3] = { (s[0]+s[3])*invN, (s[1]+s[4])*invN, (s[2]+s[5])*invN };
    float X[9];
#pragma unroll
    for (int i = 0; i < 3; i++)
#pragma unroll
      for (int j = 0; j < 3; j++)
        X[i*3+j] = s[6 + i*3 + j] - (float)N_ * cB[i] * cA[j];
    float fn = 0.f;
#pragma unroll
    for (int i = 0; i < 9; i++) fn += X[i]*X[i];
    float scl = rsqrtf(fn);
#pragma unroll
    for (int i = 0; i < 9; i++) X[i] *= scl;
    for (int it = 0; it < 24; it++) {
      float c00 =  X[4]*X[8]-X[5]*X[7];
      float c01 = -(X[3]*X[8]-X[5]*X[6]);
      float c02 =  X[3]*X[7]-X[4]*X[6];
      float c10 = -(X[1]*X[8]-X[2]*X[7]);
      float c11 =  X[0]*X[8]-X[2]*X[6];
      float c12_= -(X[0]*X[7]-X[1]*X[6]);
      float c20 =  X[1]*X[5]-X[2]*X[4];
      float c21 = -(X[0]*X[5]-X[2]*X[3]);
      float c22 =  X[0]*X[4]-X[1]*X[3];
      float det = X[0]*c00 + X[1]*c01 + X[2]*c02;
      float id = 0.5f / det;
      X[0]=0.5f*X[0]+c00*id; X[1]=0.5f*X[1]+c01*id; X[2]=0.5f*X[2]+c02*id;
      X[3]=0.5f*X[3]+c10*id; X[4]=0.5f*X[4]+c11*id; X[5]=0.5f*X[5]+c12_*id;
      X[6]=0.5f*X[6]+c20*id; X[7]=0.5f*X[7]+c21*id; X[8]=0.5f*X[8]+c22*id;
    }
    float tt[3];
#pragma unroll
    for (int k = 0; k < 3; k++)
      tt[k] = cA[k] - (cB[0]*X[k] + cB[1]*X[3+k] + cB[2]*X[6+k]) + myY[k];
#pragma unroll
    for (int k = 0; k < 3; k++) {
      float v = fmaf(x30, X[k], fmaf(x31, X[3+k], fmaf(x32, X[6+k], tt[k])));
      out[(size_t)t*3 + k] = v;
    }
  }
}

extern "C" void kernel_launch(void* const* d_in, const int* in_sizes, int n_in,
                              void* d_out, int out_size, void* d_ws, size_t ws_size,
                              hipStream_t stream) {
  const float* x_orig = (const float*)d_in[0];
  const float* y_orig = (const float*)d_in[1];
  const float* W_in   = (const float*)d_in[2];
  const float* b_in   = (const float*)d_in[3];
  const float* Wqkv_s = (const float*)d_in[4];
  const float* bqkv_s = (const float*)d_in[5];
  const float* Wo_s   = (const float*)d_in[6];
  const float* bo_s   = (const float*)d_in[7];
  const float* Wqkv_c = (const float*)d_in[8];
  const float* bqkv_c = (const float*)d_in[9];
  const float* Wo_c   = (const float*)d_in[10];
  const float* bo_c   = (const float*)d_in[11];
  const float* W_out  = (const float*)d_in[12];
  const float* b_out  = (const float*)d_in[13];
  unsigned long long* ws = (unsigned long long*)d_ws;

  k_all<<<256, 128, 0, stream>>>(x_orig, y_orig, W_in, b_in, Wqkv_s, bqkv_s,
                                 Wo_s, bo_s, Wqkv_c, bqkv_c, Wo_c, bo_c,
                                 W_out, b_out, ws, (float*)d_out);
}

// Round 5
// 111.531 us; speedup vs baseline: 1.3489x; 1.0708x over previous
//
#include <hip/hip_runtime.h>

#define B_ 16
#define N_ 1024
#define F_ 16
#define E_ 12
#define H_ 4

// workspace layout (float offsets). Data = plain fp32 in relaxed agent atomic slots
// (write-once, read-once); readiness = one tagged u64 flag per producer block.
#define OFF_PS 0        // 45056: self raw moments + x-sums per chunk [side*16+b][chunk8][176]
#define OFF_PC 45056    // 20480: cross moments per chunk [b][chunk8][160]
#define OFF_PK 65536    //  2048: Kabsch partial stats [b][chunk8][16] (15 used)
#define OFF_FLAG 67584  // u64 flags: flS[32*8] | flC[16*8] | flK[16*8]

#define TAG_S 0x51A7E00Dull
#define TAG_C 0x51A7E0C5ull
#define TAG_K 0x51A7E0B3ull

// moment layout per unit (39 used):
// [0:3]=Sum k | [3:9]=Sum kk (00,11,22,01,02,12) | [9:12]=Sum v
// [12:21]=Sum k_i v_c | [21:39]=Sum kk_pair v_c
// partS cols: [h*40 + j] for j<39, plus [160:176] = Sum x (16 features)

// shared-weight offsets
#define SW_WIN   0      // 192
#define SW_BIN   192    // 12
#define SW_WQKVS 204    // 432
#define SW_BQKVS 636    // 36
#define SW_WOS   672    // 144
#define SW_BOS   816    // 12
#define SW_WQKVC 828    // 432
#define SW_BQKVC 1260   // 36
#define SW_WOC   1296   // 144
#define SW_BOC   1440   // 12
#define SW_WOUT  1452   // 36
#define SW_BOUT  1488   // 3
#define SW_TOT   1491

__device__ __forceinline__ void data_store(float* p, float v) {
  __hip_atomic_store((unsigned*)p, __float_as_uint(v),
                     __ATOMIC_RELAXED, __HIP_MEMORY_SCOPE_AGENT);
}
__device__ __forceinline__ float data_load(const float* p) {
  unsigned u = __hip_atomic_load((const unsigned*)p,
                                 __ATOMIC_RELAXED, __HIP_MEMORY_SCOPE_AGENT);
  return __uint_as_float(u);
}
// producer: call AFTER __syncthreads() (which drains vmcnt for all waves)
__device__ __forceinline__ void flag_set(unsigned long long* f, unsigned long long tag) {
  __hip_atomic_store(f, tag, __ATOMIC_RELAXED, __HIP_MEMORY_SCOPE_AGENT);
}
__device__ __forceinline__ void flag_wait(unsigned long long* f, unsigned long long tag) {
  while (__hip_atomic_load(f, __ATOMIC_RELAXED, __HIP_MEMORY_SCOPE_AGENT) != tag)
    __builtin_amdgcn_s_sleep(2);
  asm volatile("" ::: "memory");    // no hoisting of data loads above readiness
}

__device__ __forceinline__ void mom_compute(float k0, float k1, float k2,
                                            float v0, float v1, float v2, float* m) {
  m[0]=k0; m[1]=k1; m[2]=k2;
  float s00=k0*k0, s11=k1*k1, s22=k2*k2, s01=k0*k1, s02=k0*k2, s12=k1*k2;
  m[3]=s00; m[4]=s11; m[5]=s22; m[6]=s01; m[7]=s02; m[8]=s12;
  m[9]=v0; m[10]=v1; m[11]=v2;
  m[12]=k0*v0; m[13]=k0*v1; m[14]=k0*v2;
  m[15]=k1*v0; m[16]=k1*v1; m[17]=k1*v2;
  m[18]=k2*v0; m[19]=k2*v1; m[20]=k2*v2;
  m[21]=s00*v0; m[22]=s00*v1; m[23]=s00*v2;
  m[24]=s11*v0; m[25]=s11*v1; m[26]=s11*v2;
  m[27]=s22*v0; m[28]=s22*v1; m[29]=s22*v2;
  m[30]=s01*v0; m[31]=s01*v1; m[32]=s01*v2;
  m[33]=s02*v0; m[34]=s02*v1; m[35]=s02*v2;
  m[36]=s12*v0; m[37]=s12*v1; m[38]=s12*v2;
}

// eval with pre-scaled moments (diag 2nd-order entries x0.5 applied at smu stage)
__device__ __forceinline__ void attn_eval(const float* __restrict__ mu,
                                          float p0, float p1, float p2, float* out) {
  float pp0=p0*p0, pp1=p1*p1, pp2=p2*p2;
  float q01=p0*p1, q02=p0*p2, q12=p1*p2;
  float den = (float)N_;
  den = fmaf(p0, mu[0], den); den = fmaf(p1, mu[1], den); den = fmaf(p2, mu[2], den);
  den = fmaf(pp0, mu[3], den); den = fmaf(pp1, mu[4], den); den = fmaf(pp2, mu[5], den);
  den = fmaf(q01, mu[6], den); den = fmaf(q02, mu[7], den); den = fmaf(q12, mu[8], den);
  float inv = 1.0f / den;
#pragma unroll
  for (int c = 0; c < 3; c++) {
    float num = mu[9+c];
    num = fmaf(p0, mu[12+c], num); num = fmaf(p1, mu[15+c], num); num = fmaf(p2, mu[18+c], num);
    num = fmaf(pp0, mu[21+c], num); num = fmaf(pp1, mu[24+c], num); num = fmaf(pp2, mu[27+c], num);
    num = fmaf(q01, mu[30+c], num); num = fmaf(q02, mu[33+c], num); num = fmaf(q12, mu[36+c], num);
    out[c] = num * inv;
  }
}

__device__ __forceinline__ float mom_scale(int j) {
  return ((j >= 3 && j < 6) || (j >= 21 && j < 30)) ? 0.5f : 1.0f;
}

// ---- single kernel: A(proj) / B(self-attn+cross-proj) / C(cross-attn+stats) / D(polar+transform)
__global__ __launch_bounds__(128, 1)
void k_all(const float* __restrict__ xo, const float* __restrict__ yo,
           const float* __restrict__ W_in, const float* __restrict__ b_in,
           const float* __restrict__ Wqkv_s, const float* __restrict__ bqkv_s,
           const float* __restrict__ Wo_s, const float* __restrict__ bo_s,
           const float* __restrict__ Wqkv_c, const float* __restrict__ bqkv_c,
           const float* __restrict__ Wo_c, const float* __restrict__ bo_c,
           const float* __restrict__ W_out, const float* __restrict__ b_out,
           float* __restrict__ ws, float* __restrict__ out) {
  __shared__ float sw[SW_TOT];
  __shared__ float red[32 * 180];   // [quad32][176 used, stride 180]
  __shared__ float rawR[176];       // raw sums for this (side,b) — persists B..D
  __shared__ float smu[160];        // self moments (B), reused for cross moments (C)
  __shared__ float dq[12];
  __shared__ float sredK[2][15];
  __shared__ float sstats[15];
  __shared__ float myY[3];          // y mean (first 3 comps) — persists C..D

  float* psS = ws + OFF_PS;
  float* psC = ws + OFF_PC;
  float* psK = ws + OFF_PK;
  unsigned long long* flS = (unsigned long long*)(ws + OFF_FLAG);
  unsigned long long* flC = flS + 32*8;
  unsigned long long* flK = flC + 16*8;

  int tid = threadIdx.x;
  int blk = blockIdx.x;
  int side = blk >> 7;
  int rem  = blk & 127;
  int b = rem >> 3, c = rem & 7;
  int n = c * 128 + tid;
  int t = b * N_ + n;
  int g = side*16 + b;              // partS group
  int qd = tid >> 2;
  bool rep = (tid & 3) == 0;
  const float SC = 0.57735026918962584f;   // 1/sqrt(3)
  const float invN = 1.0f / N_;

  // registers carried across phases
  float qreg[12];                   // raw self-q per head (A -> B)
  float qc[12];                     // cross-q per head (B -> C, x side)
  float x30 = 0.f, x31 = 0.f, x32 = 0.f;  // centered x3 (C -> D, x side)

  // ---- load all weights once ----
  for (int i = tid; i < SW_TOT; i += 128) {
    float v;
    if (i < 192)       v = W_in[i];
    else if (i < 204)  v = b_in[i - 192];
    else if (i < 636)  v = Wqkv_s[i - 204];
    else if (i < 672)  v = bqkv_s[i - 636];
    else if (i < 816)  v = Wo_s[i - 672];
    else if (i < 828)  v = bo_s[i - 816];
    else if (i < 1260) v = Wqkv_c[i - 828];
    else if (i < 1296) v = bqkv_c[i - 1260];
    else if (i < 1440) v = Wo_c[i - 1296];
    else if (i < 1452) v = bo_c[i - 1440];
    else if (i < 1488) v = W_out[i - 1452];
    else               v = b_out[i - 1488];
    sw[i] = v;
  }

  // ================= Phase A: raw proj + self QKV + raw moments =================
  const float* in = (side ? yo : xo) + (size_t)t * F_;
  float xv[F_];
  {
    const float4* p = (const float4*)in;
#pragma unroll
    for (int q = 0; q < 4; q++) {
      float4 v = p[q];
      xv[4*q+0]=v.x; xv[4*q+1]=v.y; xv[4*q+2]=v.z; xv[4*q+3]=v.w;
    }
  }
  __syncthreads();          // sw ready
  float xi[E_];             // raw (uncentered) xi' = x@W_in^T + b_in
#pragma unroll
  for (int e = 0; e < E_; e++) {
    float s = sw[SW_BIN + e];
#pragma unroll
    for (int f = 0; f < F_; f++) s = fmaf(xv[f], sw[SW_WIN + e*F_ + f], s);
    xi[e] = s;
  }
#pragma unroll
  for (int h = 0; h < H_; h++) {
    float qkv[9];
#pragma unroll
    for (int d = 0; d < 9; d++) {
      int o = (d/3)*12 + h*3 + (d%3);   // q=h*3+c, k=12+h*3+c, v=24+h*3+c
      float s = sw[SW_BQKVS + o];
#pragma unroll
      for (int e = 0; e < E_; e++) s = fmaf(xi[e], sw[SW_WQKVS + o*E_ + e], s);
      qkv[d] = s;
    }
#pragma unroll
    for (int d = 0; d < 3; d++) qreg[h*3+d] = qkv[d];
    float m[40];
    mom_compute(qkv[3], qkv[4], qkv[5], qkv[6], qkv[7], qkv[8], m);
    m[39] = 0.f;
#pragma unroll
    for (int j = 0; j < 39; j++) {
      m[j] += __shfl_xor(m[j], 1);
      m[j] += __shfl_xor(m[j], 2);
    }
    if (rep) {
#pragma unroll
      for (int j4 = 0; j4 < 10; j4++)
        *(float4*)&red[qd*180 + h*40 + j4*4] =
          make_float4(m[j4*4], m[j4*4+1], m[j4*4+2], m[j4*4+3]);
    }
  }
  {
    float s[F_];
#pragma unroll
    for (int f = 0; f < F_; f++) {
      float v = xv[f];
      v += __shfl_xor(v, 1);
      v += __shfl_xor(v, 2);
      s[f] = v;
    }
    if (rep) {
#pragma unroll
      for (int j4 = 0; j4 < 4; j4++)
        *(float4*)&red[qd*180 + 160 + j4*4] =
          make_float4(s[j4*4], s[j4*4+1], s[j4*4+2], s[j4*4+3]);
    }
  }
  __syncthreads();
  for (int col = tid; col < 176; col += 128) {
    float a = 0.f;
#pragma unroll
    for (int qq = 0; qq < 32; qq++) a += red[qq*180 + col];
    data_store(&psS[((size_t)g*8 + c)*176 + col], a);
  }
  __syncthreads();                          // drains vmcnt for both waves
  if (tid == 0) flag_set(&flS[g*8 + c], TAG_S);

  // ================= Phase B: moment correction + self-attn + cross QKV =================
  if (tid < 8) flag_wait(&flS[g*8 + tid], TAG_S);
  __syncthreads();
  for (int col = tid; col < 176; col += 128) {
    float a = 0.f;
#pragma unroll
    for (int cc = 0; cc < 8; cc++)
      a += data_load(&psS[((size_t)g*8 + cc)*176 + col]);
    rawR[col] = a;
  }
  __syncthreads();
  if (tid < H_) {
    int h = tid;
    const float Nf = (float)N_;
    float del[E_];               // delta = mu @ W_in^T   (no bias)
#pragma unroll
    for (int e = 0; e < E_; e++) {
      float s = 0.f;
#pragma unroll
      for (int f = 0; f < F_; f++) s = fmaf(rawR[160+f], sw[SW_WIN + e*F_ + f], s);
      del[e] = s * invN;
    }
    float A[3], G[3];            // k-shift, v-shift for this head
#pragma unroll
    for (int d = 0; d < 3; d++) {
      float sq=0.f, sk=0.f, sv=0.f;
#pragma unroll
      for (int e = 0; e < E_; e++) {
        sq = fmaf(del[e], sw[SW_WQKVS + (h*3+d)*E_ + e], sq);
        sk = fmaf(del[e], sw[SW_WQKVS + (12 + h*3+d)*E_ + e], sk);
        sv = fmaf(del[e], sw[SW_WQKVS + (24 + h*3+d)*E_ + e], sv);
      }
      dq[h*3+d] = sq; A[d] = sk; G[d] = sv;
    }
    const float* R = &rawR[h*40];
    float S[39];
#pragma unroll
    for (int i = 0; i < 3; i++) S[i] = R[i] - Nf*A[i];
    const int PI[6] = {0,1,2,0,0,1}, PJ[6] = {0,1,2,1,2,2};
#pragma unroll
    for (int p = 0; p < 6; p++) {
      int i = PI[p], j = PJ[p];
      S[3+p] = R[3+p] - A[i]*R[j] - A[j]*R[i] + Nf*A[i]*A[j];
    }
#pragma unroll
    for (int cc = 0; cc < 3; cc++) S[9+cc] = R[9+cc] - Nf*G[cc];
#pragma unroll
    for (int i = 0; i < 3; i++)
#pragma unroll
      for (int cc = 0; cc < 3; cc++)
        S[12+i*3+cc] = R[12+i*3+cc] - A[i]*R[9+cc] - G[cc]*R[i] + Nf*A[i]*G[cc];
#pragma unroll
    for (int p = 0; p < 6; p++) {
      int i = PI[p], j = PJ[p];
#pragma unroll
      for (int cc = 0; cc < 3; cc++) {
        S[21+p*3+cc] = R[21+p*3+cc]
                     - A[i]*R[12+j*3+cc] - A[j]*R[12+i*3+cc]
                     - G[cc]*R[3+p]
                     + A[i]*A[j]*R[9+cc]
                     + A[i]*G[cc]*R[j] + A[j]*G[cc]*R[i]
                     - Nf*A[i]*A[j]*G[cc];
      }
    }
#pragma unroll
    for (int j = 0; j < 39; j++) smu[h*40+j] = S[j] * mom_scale(j);
    smu[h*40+39] = 0.f;
  }
  __syncthreads();
  {
    float attn[E_];
#pragma unroll
    for (int h = 0; h < H_; h++) {
      float p0 = (qreg[h*3+0] - dq[h*3+0]) * SC;
      float p1 = (qreg[h*3+1] - dq[h*3+1]) * SC;
      float p2 = (qreg[h*3+2] - dq[h*3+2]) * SC;
      attn_eval(&smu[h*40], p0, p1, p2, &attn[h*3]);
    }
    float i2[E_];
#pragma unroll
    for (int e = 0; e < E_; e++) {
      float s = sw[SW_BOS + e];
#pragma unroll
      for (int j = 0; j < E_; j++) s = fmaf(attn[j], sw[SW_WOS + e*E_ + j], s);
      i2[e] = s;
    }
    if (!side) {                      // x side -> cross-q stays in registers
#pragma unroll
      for (int o = 0; o < 12; o++) {
        float s = sw[SW_BQKVC + o];
#pragma unroll
        for (int e = 0; e < E_; e++) s = fmaf(i2[e], sw[SW_WQKVC + o*E_ + e], s);
        qc[o] = s;
      }
    } else {                          // y side -> cross moments (centered, no fixup)
#pragma unroll
      for (int h = 0; h < H_; h++) {
        float kv[6];
#pragma unroll
        for (int d = 0; d < 6; d++) {
          int o = 12 + (d/3)*12 + h*3 + (d%3);
          float s = sw[SW_BQKVC + o];
#pragma unroll
          for (int e = 0; e < E_; e++) s = fmaf(i2[e], sw[SW_WQKVC + o*E_ + e], s);
          kv[d] = s;
        }
        float m[40];
        mom_compute(kv[0], kv[1], kv[2], kv[3], kv[4], kv[5], m);
        m[39] = 0.f;
#pragma unroll
        for (int j = 0; j < 39; j++) {
          m[j] += __shfl_xor(m[j], 1);
          m[j] += __shfl_xor(m[j], 2);
        }
        if (rep) {
#pragma unroll
          for (int j4 = 0; j4 < 10; j4++)
            *(float4*)&red[qd*180 + h*40 + j4*4] =
              make_float4(m[j4*4], m[j4*4+1], m[j4*4+2], m[j4*4+3]);
        }
      }
      __syncthreads();                // block-uniform branch (side per block)
      for (int col = tid; col < 160; col += 128) {
        float a = 0.f;
#pragma unroll
        for (int qq = 0; qq < 32; qq++) a += red[qq*180 + col];
        data_store(&psC[((size_t)b*8 + c)*160 + col], a);
      }
      __syncthreads();                // drains vmcnt
      if (tid == 0) flag_set(&flC[b*8 + c], TAG_C);
      return;                         // y blocks done
    }
  }

  // ================= Phase C: cross-attn + Kabsch partial stats (x blocks) =================
  {
    if (tid < 8) flag_wait(&flC[b*8 + tid], TAG_C);
    else if (tid < 16) flag_wait(&flS[(16 + b)*8 + (tid - 8)], TAG_S);  // y-side sums
    __syncthreads();
    for (int col = tid; col < 160; col += 128) {
      float a = 0.f;
#pragma unroll
      for (int cc = 0; cc < 8; cc++)
        a += data_load(&psC[((size_t)b*8 + cc)*160 + col]);
      int j = col - (col/40)*40;
      smu[col] = a * mom_scale(j);
    }
    if (tid < 3) {
      float a = 0.f;
#pragma unroll
      for (int cc = 0; cc < 8; cc++)
        a += data_load(&psS[((size_t)(16 + b)*8 + cc)*176 + 160 + tid]);
      myY[tid] = a * invN;
    }
    __syncthreads();
    float attn[E_];
#pragma unroll
    for (int h = 0; h < H_; h++) {
      float p0 = qc[h*3+0] * SC;
      float p1 = qc[h*3+1] * SC;
      float p2 = qc[h*3+2] * SC;
      attn_eval(&smu[h*40], p0, p1, p2, &attn[h*3]);
    }
    float c12[E_];
#pragma unroll
    for (int e = 0; e < E_; e++) {
      float s = sw[SW_BOC + e];
#pragma unroll
      for (int j = 0; j < E_; j++) s = fmaf(attn[j], sw[SW_WOC + e*E_ + j], s);
      c12[e] = s;
    }
    float co[3];
#pragma unroll
    for (int k = 0; k < 3; k++) {
      float s = sw[SW_BOUT + k];
#pragma unroll
      for (int e = 0; e < E_; e++) s = fmaf(c12[e], sw[SW_WOUT + k*E_ + e], s);
      co[k] = s;
    }
    x30 = xv[0] - rawR[160] * invN;   // rawR persists from phase B (this block: x sums)
    x31 = xv[1] - rawR[161] * invN;
    x32 = xv[2] - rawR[162] * invN;
    float A0 = co[0]+x30, A1 = co[1]+x31, A2 = co[2]+x32;
    float st[15];
    st[0]=co[0]; st[1]=co[1]; st[2]=co[2];
    st[3]=x30; st[4]=x31; st[5]=x32;
    st[6]=x30*A0;  st[7]=x30*A1;  st[8]=x30*A2;
    st[9]=x31*A0;  st[10]=x31*A1; st[11]=x31*A2;
    st[12]=x32*A0; st[13]=x32*A1; st[14]=x32*A2;
#pragma unroll
    for (int i = 0; i < 15; i++) {
      st[i] += __shfl_down(st[i], 32); st[i] += __shfl_down(st[i], 16);
      st[i] += __shfl_down(st[i], 8);  st[i] += __shfl_down(st[i], 4);
      st[i] += __shfl_down(st[i], 2);  st[i] += __shfl_down(st[i], 1);
    }
    int wv = tid >> 6;
    if ((tid & 63) == 0) {
#pragma unroll
      for (int i = 0; i < 15; i++) sredK[wv][i] = st[i];
    }
    __syncthreads();
    if (tid < 15)
      data_store(&psK[((size_t)b*8 + c)*16 + tid], sredK[0][tid] + sredK[1][tid]);
    __syncthreads();                  // drains vmcnt
    if (tid == 0) flag_set(&flK[b*8 + c], TAG_K);
  }

  // ================= Phase D: polar + rigid transform (x blocks) =================
  {
    if (tid < 8) flag_wait(&flK[b*8 + tid], TAG_K);
    __syncthreads();
    if (tid < 15) {
      float a = 0.f;
#pragma unroll
      for (int cc = 0; cc < 8; cc++)
        a += data_load(&psK[((size_t)b*8 + cc)*16 + tid]);
      sstats[tid] = a;
    }
    __syncthreads();
    const float* s = sstats;
    float cB[3] = { s[3]*invN, s[4]*invN, s[5]*invN };
    float cA[3] = { (s[0]+s[3])*invN, (s[1]+s[4])*invN, (s[2]+s[5])*invN };
    float X[9];
#pragma unroll
    for (int i = 0; i < 3; i++)
#pragma unroll
      for (int j = 0; j < 3; j++)
        X[i*3+j] = s[6 + i*3 + j] - (float)N_ * cB[i] * cA[j];
    float fn = 0.f;
#pragma unroll
    for (int i = 0; i < 9; i++) fn += X[i]*X[i];
    float scl = rsqrtf(fn);
#pragma unroll
    for (int i = 0; i < 9; i++) X[i] *= scl;
    for (int it = 0; it < 24; it++) {
      float c00 =  X[4]*X[8]-X[5]*X[7];
      float c01 = -(X[3]*X[8]-X[5]*X[6]);
      float c02 =  X[3]*X[7]-X[4]*X[6];
      float c10 = -(X[1]*X[8]-X[2]*X[7]);
      float c11 =  X[0]*X[8]-X[2]*X[6];
      float c12_= -(X[0]*X[7]-X[1]*X[6]);
      float c20 =  X[1]*X[5]-X[2]*X[4];
      float c21 = -(X[0]*X[5]-X[2]*X[3]);
      float c22 =  X[0]*X[4]-X[1]*X[3];
      float det = X[0]*c00 + X[1]*c01 + X[2]*c02;
      float id = 0.5f / det;
      X[0]=0.5f*X[0]+c00*id; X[1]=0.5f*X[1]+c01*id; X[2]=0.5f*X[2]+c02*id;
      X[3]=0.5f*X[3]+c10*id; X[4]=0.5f*X[4]+c11*id; X[5]=0.5f*X[5]+c12_*id;
      X[6]=0.5f*X[6]+c20*id; X[7]=0.5f*X[7]+c21*id; X[8]=0.5f*X[8]+c22*id;
    }
    float tt[3];
#pragma unroll
    for (int k = 0; k < 3; k++)
      tt[k] = cA[k] - (cB[0]*X[k] + cB[1]*X[3+k] + cB[2]*X[6+k]) + myY[k];
#pragma unroll
    for (int k = 0; k < 3; k++) {
      float v = fmaf(x30, X[k], fmaf(x31, X[3+k], fmaf(x32, X[6+k], tt[k])));
      out[(size_t)t*3 + k] = v;
    }
  }
}

extern "C" void kernel_launch(void* const* d_in, const int* in_sizes, int n_in,
                              void* d_out, int out_size, void* d_ws, size_t ws_size,
                              hipStream_t stream) {
  const float* x_orig = (const float*)d_in[0];
  const float* y_orig = (const float*)d_in[1];
  const float* W_in   = (const float*)d_in[2];
  const float* b_in   = (const float*)d_in[3];
  const float* Wqkv_s = (const float*)d_in[4];
  const float* bqkv_s = (const float*)d_in[5];
  const float* Wo_s   = (const float*)d_in[6];
  const float* bo_s   = (const float*)d_in[7];
  const float* Wqkv_c = (const float*)d_in[8];
  const float* bqkv_c = (const float*)d_in[9];
  const float* Wo_c   = (const float*)d_in[10];
  const float* bo_c   = (const float*)d_in[11];
  const float* W_out  = (const float*)d_in[12];
  const float* b_out  = (const float*)d_in[13];
  float* ws = (float*)d_ws;

  k_all<<<256, 128, 0, stream>>>(x_orig, y_orig, W_in, b_in, Wqkv_s, bqkv_s,
                                 Wo_s, bo_s, Wqkv_c, bqkv_c, Wo_c, bo_c,
                                 W_out, b_out, ws, (float*)d_out);
}